// Round 4
// baseline (730.564 us; speedup 1.0000x reference)
//
#include <hip/hip_runtime.h>
#include <stdint.h>

typedef float f32x4 __attribute__((ext_vector_type(4)));
typedef __bf16 bf16x8 __attribute__((ext_vector_type(8)));
typedef unsigned short u16x4 __attribute__((ext_vector_type(4)));
typedef unsigned short u16x8 __attribute__((ext_vector_type(8)));

#define B_ROWS 16384
#define IN_DIM 512
#define HID_DIM 1024
#define OUT_DIM 512
#define K_CAT 1536   // IN + HID
#define NT (K_CAT / 64)  // 24 K-tiles of 64

// ---------- helpers ----------

__device__ __forceinline__ unsigned short f2bf(float f) {
  unsigned u = __builtin_bit_cast(unsigned, f);
  unsigned r = u + 0x7fffu + ((u >> 16) & 1u);  // RNE
  return (unsigned short)(r >> 16);
}

__device__ __forceinline__ float sigmoidf_(float x) {
  return 1.f / (1.f + __expf(-x));
}
__device__ __forceinline__ float tanhf_(float x) {
  return 2.f / (1.f + __expf(-2.f * x)) - 1.f;
}

// async global->LDS, 16B per lane; LDS dest = wave-uniform base + lane*16
__device__ __forceinline__ void async16(const void* g, void* l) {
  const __attribute__((address_space(1))) unsigned int* gp =
      reinterpret_cast<const __attribute__((address_space(1))) unsigned int*>(
          reinterpret_cast<uintptr_t>(g));
  __attribute__((address_space(3))) unsigned int* lp =
      reinterpret_cast<__attribute__((address_space(3))) unsigned int*>(
          reinterpret_cast<uintptr_t>(l));
  __builtin_amdgcn_global_load_lds(gp, lp, 16, 0, 0);
}

// swizzled LDS fragment read: tile rows are 64 bf16 (128B = 8 x 16B slots),
// storage slot = logical kslot ^ (row & 7). Source side applies the same
// involution (pre-swizzled global address), LDS stays linear for
// global_load_lds (rule: both-sides-or-neither).
__device__ __forceinline__ bf16x8 frag_ld(const unsigned short* base, int row,
                                          int kslot) {
  return *(const bf16x8*)(base + row * 64 + (((kslot) ^ (row & 7)) << 3));
}

// ---------- P1: cast x||h -> bf16 A[16384][1536], fc_w -> bf16 ----------
// grid: 12544 * 256 threads == 3,145,728 (A/8) + 65,536 (fcw/8) exactly.

__global__ void prep_cast_kernel(const float* __restrict__ x,
                                 const float* __restrict__ h,
                                 const float* __restrict__ fcw,
                                 unsigned short* __restrict__ A,
                                 unsigned short* __restrict__ fcw16) {
  int gid = blockIdx.x * 256 + threadIdx.x;
  const int NA = B_ROWS * K_CAT / 8;
  const float* src;
  unsigned short* dst;
  if (gid < NA) {
    int flat = gid * 8;
    int row = flat / K_CAT;
    int col = flat - row * K_CAT;
    src = (col < IN_DIM) ? (x + (size_t)row * IN_DIM + col)
                         : (h + (size_t)row * HID_DIM + (col - IN_DIM));
    dst = A + flat;
  } else {
    int j = (gid - NA) * 8;
    src = fcw + j;
    dst = fcw16 + j;
  }
  f32x4 v0 = *(const f32x4*)src;
  f32x4 v1 = *(const f32x4*)(src + 4);
  u16x8 o;
  o[0] = f2bf(v0[0]); o[1] = f2bf(v0[1]); o[2] = f2bf(v0[2]); o[3] = f2bf(v0[3]);
  o[4] = f2bf(v1[0]); o[5] = f2bf(v1[1]); o[6] = f2bf(v1[2]); o[7] = f2bf(v1[3]);
  *(u16x8*)dst = o;
}

// ---------- P2: pack Wt[nb][k] bf16, nb = (h>>6)*256 + gate*64 + (h&63) ----
// So a 256-wide N-tile of the gates GEMM = all 4 gates x 64 h-columns.
// k < 512 -> W_g[k][h], else U_g[k-512][h]. Tiled transpose, block 256.

__global__ void pack_w_kernel(const float* __restrict__ W0, const float* __restrict__ W1,
                              const float* __restrict__ W2, const float* __restrict__ W3,
                              const float* __restrict__ U0, const float* __restrict__ U1,
                              const float* __restrict__ U2, const float* __restrict__ U3,
                              unsigned short* __restrict__ Wt) {
  __shared__ float tile[32][33];
  int g = blockIdx.z;
  int n0 = blockIdx.x * 32;
  int k0 = blockIdx.y * 32;
  const float* Wg = g == 0 ? W0 : g == 1 ? W1 : g == 2 ? W2 : W3;
  const float* Ug = g == 0 ? U0 : g == 1 ? U1 : g == 2 ? U2 : U3;
  int tx = threadIdx.x & 31, ty = threadIdx.x >> 5;
#pragma unroll
  for (int i = 0; i < 4; ++i) {
    int ky = ty + i * 8;
    int k = k0 + ky;
    float v = (k < IN_DIM) ? Wg[(size_t)k * HID_DIM + n0 + tx]
                           : Ug[(size_t)(k - IN_DIM) * HID_DIM + n0 + tx];
    tile[ky][tx] = v;
  }
  __syncthreads();
#pragma unroll
  for (int i = 0; i < 4; ++i) {
    int n = n0 + ty + i * 8;
    int nb = ((n >> 6) << 8) + (g << 6) + (n & 63);
    Wt[(size_t)nb * K_CAT + k0 + tx] = f2bf(tile[tx][ty + i * 8]);
  }
}

// ---------- G1: fused gates GEMM + LSTM cell, 256^2 8-phase schedule -------
// Block = 512 threads (8 waves, 2M x 4N). Tile 256 rows x 256 packed cols
// (= 64 h-cols x 4 gates) over K=1536, BK=64, double-buffered 128KB LDS.
// Staging: 8 rounds/tile (1 global_load_lds x 16B per thread per round):
// rounds 0-3 = B rows [64r,64r+64), rounds 4-7 = A row-groups {0,2,1,3}.
// K-tile = 4 TRUE phases (m201 discipline), each:
//   {ds_read frags; issue 2 rounds; s_barrier; lgkmcnt(0);
//    setprio(1) 16xMFMA setprio(0); [vmcnt at q1/q3 end]; s_barrier}
// The per-phase double barrier is the scheduling fence that pins the
// alternating ds_read / MFMA interleave (m196: coarse split loses 7-27%;
// m218b: setprio only pays with the phase role-split).
// Counted vmcnt, never 0 in main loop (FIFO per-wave, 8 issues/tile):
//   q1-end: vmcnt(4) -> this tile's rounds 6,7 landed (q2/q3 read them)
//   q3-end: vmcnt(2) -> next tile's rounds 0-5 landed (next q0/q1 read them)
// Tail tile: vmcnt(0) at q1-end, no trailing wait.
// LDS bank fix: storage slot = kslot ^ (row&7) via pre-swizzled global source
// (linear global_load_lds dest) + same XOR on ds_read.

template <int TAIL>
__device__ __forceinline__ void ktile(unsigned short* stage, int cur,
                                      const unsigned short* (&gp)[8],
                                      const int (&ldsoff)[8], int wm, int wn,
                                      int lane16, int quad, f32x4 (&acc)[8][4]) {
  const unsigned short* sB = stage + cur * 32768;
  const unsigned short* sA = sB + 16384;
  const int nxt = (cur ^ 1) * 65536;  // bytes
  bf16x8 bfr[4][2], af[2][2];

#define ISSUE_(r)                                     \
  if (!TAIL) {                                        \
    async16(gp[r], (char*)stage + nxt + ldsoff[r]);   \
    gp[r] += 64;                                      \
  }

#define READ_A_(q)                                    \
  {                                                   \
    const int r0 = wm * 128 + (q) * 32 + lane16;      \
    af[0][0] = frag_ld(sA, r0, quad);                 \
    af[0][1] = frag_ld(sA, r0, 4 + quad);             \
    af[1][0] = frag_ld(sA, r0 + 16, quad);            \
    af[1][1] = frag_ld(sA, r0 + 16, 4 + quad);        \
  }

#define MFMA_Q_(q)                                                        \
  __builtin_amdgcn_s_setprio(1);                                          \
  _Pragma("unroll") for (int nt = 0; nt < 4; ++nt) {                      \
    acc[2 * (q)][nt] = __builtin_amdgcn_mfma_f32_16x16x32_bf16(           \
        af[0][0], bfr[nt][0], acc[2 * (q)][nt], 0, 0, 0);                 \
    acc[2 * (q)][nt] = __builtin_amdgcn_mfma_f32_16x16x32_bf16(           \
        af[0][1], bfr[nt][1], acc[2 * (q)][nt], 0, 0, 0);                 \
    acc[2 * (q) + 1][nt] = __builtin_amdgcn_mfma_f32_16x16x32_bf16(       \
        af[1][0], bfr[nt][0], acc[2 * (q) + 1][nt], 0, 0, 0);             \
    acc[2 * (q) + 1][nt] = __builtin_amdgcn_mfma_f32_16x16x32_bf16(       \
        af[1][1], bfr[nt][1], acc[2 * (q) + 1][nt], 0, 0, 0);             \
  }                                                                       \
  __builtin_amdgcn_s_setprio(0);

#define PHASE_SYNC_                                   \
  __builtin_amdgcn_s_barrier();                       \
  asm volatile("s_waitcnt lgkmcnt(0)" ::: "memory");

  // ---- q0 ---- (entry guaranteed by prev q3-end / prologue vmcnt(2)+barrier)
#pragma unroll
  for (int nt = 0; nt < 4; ++nt) {
    const int rb = wn * 64 + nt * 16 + lane16;
    bfr[nt][0] = frag_ld(sB, rb, quad);
    bfr[nt][1] = frag_ld(sB, rb, 4 + quad);
  }
  READ_A_(0);
  ISSUE_(0); ISSUE_(1);
  PHASE_SYNC_;
  MFMA_Q_(0);
  __builtin_amdgcn_s_barrier();
  // ---- q1 ----
  READ_A_(1);
  ISSUE_(2); ISSUE_(3);
  PHASE_SYNC_;
  MFMA_Q_(1);
  if (TAIL) {
    asm volatile("s_waitcnt vmcnt(0)" ::: "memory");
  } else {
    asm volatile("s_waitcnt vmcnt(4)" ::: "memory");
  }
  __builtin_amdgcn_s_barrier();
  // ---- q2 ----
  READ_A_(2);
  ISSUE_(4); ISSUE_(5);
  PHASE_SYNC_;
  MFMA_Q_(2);
  __builtin_amdgcn_s_barrier();
  // ---- q3 ----
  READ_A_(3);
  ISSUE_(6); ISSUE_(7);
  PHASE_SYNC_;
  MFMA_Q_(3);
  if (!TAIL) {
    asm volatile("s_waitcnt vmcnt(2)" ::: "memory");
  }
  __builtin_amdgcn_s_barrier();

#undef ISSUE_
#undef READ_A_
#undef MFMA_Q_
#undef PHASE_SYNC_
}

__global__ __launch_bounds__(512, 2) void lstm_gates_kernel(
    const unsigned short* __restrict__ A,   // [16384][1536] bf16
    const unsigned short* __restrict__ Wt,  // [4096][1536] bf16, packed rows
    const float* __restrict__ c_t,
    const float* __restrict__ b_i, const float* __restrict__ b_f,
    const float* __restrict__ b_o, const float* __restrict__ b_c,
    float* __restrict__ h_new, float* __restrict__ c_new,
    unsigned short* __restrict__ h_bf) {
  const int tid = threadIdx.x;
  const int wave = tid >> 6, lane = tid & 63;
  const int lane16 = lane & 15, quad = lane >> 4;
  const int wm = wave >> 2, wn = wave & 3;  // wave = wm*4 + wn
  const int m0 = blockIdx.x * 256;
  const int hb = blockIdx.y;  // 64 h-cols per tile

  __shared__ __align__(16) union {
    unsigned short stage[2][32768];  // per buf: B tile [256][64] | A tile [256][64]
    float act[4 * 64 * 68];          // epilogue: 4 gates x 64 rows x (64, stride 68)
  } U;

  // ---- staging setup: thread covers LDS bytes region + tid*16 ----
  const int srow = tid >> 3;   // row within a 64-row group
  const int sslot = tid & 7;   // 16B slot within a 128B row
  const int swz = (sslot ^ (srow & 7)) << 3;  // pre-swizzled source elem offset
  const unsigned short* gp[8];
  int ldsoff[8];
#pragma unroll
  for (int r = 0; r < 4; ++r) {  // B rounds
    gp[r] = Wt + (size_t)(hb * 256 + r * 64 + srow) * K_CAT + swz;
    ldsoff[r] = r * 8192 + wave * 1024;
  }
  {
    const int grp[4] = {0, 2, 1, 3};  // A row-group issue order (q0/q1 first)
#pragma unroll
    for (int i = 0; i < 4; ++i) {
      gp[4 + i] = A + (size_t)(m0 + grp[i] * 64 + srow) * K_CAT + swz;
      ldsoff[4 + i] = 32768 + grp[i] * 8192 + wave * 1024;
    }
  }

  f32x4 acc[8][4];
#pragma unroll
  for (int i = 0; i < 8; ++i)
#pragma unroll
    for (int j = 0; j < 4; ++j) {
      acc[i][j][0] = 0.f; acc[i][j][1] = 0.f; acc[i][j][2] = 0.f; acc[i][j][3] = 0.f;
    }

  unsigned short* stage = &U.stage[0][0];
  // prologue: tile 0 into buf 0 (8 rounds in flight), then the tile-entry
  // contract: vmcnt(2)+barrier (rounds 0-5 of the tile about to be read).
#pragma unroll
  for (int r = 0; r < 8; ++r) {
    async16(gp[r], (char*)stage + ldsoff[r]);
    gp[r] += 64;
  }
  asm volatile("s_waitcnt vmcnt(2)" ::: "memory");
  __builtin_amdgcn_s_barrier();

  int cur = 0;
  for (int t = 0; t < NT - 1; ++t) {
    ktile<0>(stage, cur, gp, ldsoff, wm, wn, lane16, quad, acc);
    cur ^= 1;
  }
  ktile<1>(stage, cur, gp, ldsoff, wm, wn, lane16, quad, acc);

  __syncthreads();

  // ---- epilogue: activations + cell update, 4 passes of 64 rows ----
  float bv[4];
  const float* bgp = (wn == 0) ? b_i : (wn == 1) ? b_f : (wn == 2) ? b_o : b_c;
#pragma unroll
  for (int nt = 0; nt < 4; ++nt) bv[nt] = bgp[hb * 64 + nt * 16 + lane16];

#pragma unroll
  for (int c = 0; c < 4; ++c) {
    if (wm == (c >> 1)) {  // waves owning this 64-row band write their gate
#pragma unroll
      for (int mtl = 0; mtl < 4; ++mtl) {
#pragma unroll
        for (int nt = 0; nt < 4; ++nt)
#pragma unroll
          for (int r = 0; r < 4; ++r) {
            const int row = mtl * 16 + quad * 4 + r;  // 0..63 in pass
            const int col = nt * 16 + lane16;         // 0..63 h-col
            float v = acc[(c & 1) * 4 + mtl][nt][r] + bv[nt];
            float a = (wn < 3) ? sigmoidf_(v) : tanhf_(v);
            U.act[(wn * 64 + row) * 68 + col] = a;
          }
      }
    }
    __syncthreads();
    {
      const int row_l = tid >> 3;        // 0..63
      const int col0 = (tid & 7) * 8;    // 0..56
      const int grow = m0 + c * 64 + row_l;
      const size_t off = (size_t)grow * HID_DIM + hb * 64 + col0;
      u16x8 hbv;
#pragma unroll
      for (int half = 0; half < 2; ++half) {
        const int c4 = col0 + half * 4;
        f32x4 iv = *(const f32x4*)&U.act[(0 * 64 + row_l) * 68 + c4];
        f32x4 fv = *(const f32x4*)&U.act[(1 * 64 + row_l) * 68 + c4];
        f32x4 ov = *(const f32x4*)&U.act[(2 * 64 + row_l) * 68 + c4];
        f32x4 gv = *(const f32x4*)&U.act[(3 * 64 + row_l) * 68 + c4];
        f32x4 cold = *(const f32x4*)(c_t + off + half * 4);
        f32x4 cn, hn;
#pragma unroll
        for (int j = 0; j < 4; ++j) {
          float c2 = fv[j] * cold[j] + iv[j] * gv[j];
          float h2 = ov[j] * tanhf_(c2);
          cn[j] = c2;
          hn[j] = h2;
          hbv[half * 4 + j] = f2bf(h2);
        }
        *(f32x4*)(c_new + off + half * 4) = cn;
        *(f32x4*)(h_new + off + half * 4) = hn;
      }
      *(u16x8*)(h_bf + off) = hbv;
    }
    __syncthreads();
  }
}

// ---------- G2: out = h_new_bf16 @ fc_w^T + fc_b ----------
// m97-style 128x128 bt-GEMM; fc_w [512][1024] is already B^T layout.

__global__ __launch_bounds__(256, 2) void fc_kernel(
    const unsigned short* __restrict__ A,   // [16384][1024] bf16
    const unsigned short* __restrict__ Bt,  // [512][1024] bf16
    const float* __restrict__ bias, float* __restrict__ out) {
  const int m0 = blockIdx.x * 128;  // x = m: consecutive blocks share Bt slice
  const int n0 = blockIdx.y * 128;
  const int tid = threadIdx.x;
  const int wave = tid >> 6, lane = tid & 63;
  const int lane16 = lane & 15, quad = lane >> 4;
  const int wm = wave & 1, wn = wave >> 1;

  __shared__ __align__(16) unsigned short stage[8192];  // sA 128x32 | sB 128x32

  const unsigned short* gp[4];
  int ldsoff[4];
#pragma unroll
  for (int cc = 0; cc < 4; ++cc) {
    int chunk = wave * 4 + cc;
    ldsoff[cc] = chunk * 1024;
    int rr = lane >> 2;
    int col = (lane & 3) * 8;
    if (chunk < 8) {
      gp[cc] = A + (size_t)(m0 + chunk * 16 + rr) * HID_DIM + col;
    } else {
      gp[cc] = Bt + (size_t)(n0 + (chunk - 8) * 16 + rr) * HID_DIM + col;
    }
  }

  f32x4 acc[4][4];
#pragma unroll
  for (int i = 0; i < 4; ++i)
#pragma unroll
    for (int j = 0; j < 4; ++j) {
      acc[i][j][0] = 0.f; acc[i][j][1] = 0.f; acc[i][j][2] = 0.f; acc[i][j][3] = 0.f;
    }

  const unsigned short* sA = stage;
  const unsigned short* sB = stage + 4096;

  for (int kt = 0; kt < HID_DIM; kt += 32) {
#pragma unroll
    for (int cc = 0; cc < 4; ++cc) {
      async16(gp[cc], (char*)stage + ldsoff[cc]);
      gp[cc] += 32;
    }
    __syncthreads();
    bf16x8 a[4], b[4];
#pragma unroll
    for (int mt = 0; mt < 4; ++mt)
      a[mt] = *(const bf16x8*)(sA + (wm * 64 + mt * 16 + lane16) * 32 + quad * 8);
#pragma unroll
    for (int nt = 0; nt < 4; ++nt)
      b[nt] = *(const bf16x8*)(sB + (wn * 64 + nt * 16 + lane16) * 32 + quad * 8);
#pragma unroll
    for (int mt = 0; mt < 4; ++mt)
#pragma unroll
      for (int nt = 0; nt < 4; ++nt)
        acc[mt][nt] =
            __builtin_amdgcn_mfma_f32_16x16x32_bf16(a[mt], b[nt], acc[mt][nt], 0, 0, 0);
    __syncthreads();
  }

#pragma unroll
  for (int nt = 0; nt < 4; ++nt) {
    int gcol = n0 + wn * 64 + nt * 16 + lane16;
    float bb = bias[gcol];
#pragma unroll
    for (int mt = 0; mt < 4; ++mt) {
#pragma unroll
      for (int r = 0; r < 4; ++r) {
        int grow = m0 + wm * 64 + mt * 16 + quad * 4 + r;
        out[(size_t)grow * OUT_DIM + gcol] = acc[mt][nt][r] + bb;
      }
    }
  }
}

// ---------- launch ----------

extern "C" void kernel_launch(void* const* d_in, const int* in_sizes, int n_in,
                              void* d_out, int out_size, void* d_ws, size_t ws_size,
                              hipStream_t stream) {
  const float* x = (const float*)d_in[0];
  const float* h = (const float*)d_in[1];
  const float* c = (const float*)d_in[2];
  const float* W0 = (const float*)d_in[3];
  const float* U0 = (const float*)d_in[4];
  const float* b0 = (const float*)d_in[5];
  const float* W1 = (const float*)d_in[6];
  const float* U1 = (const float*)d_in[7];
  const float* b1 = (const float*)d_in[8];
  const float* W2 = (const float*)d_in[9];
  const float* U2 = (const float*)d_in[10];
  const float* b2 = (const float*)d_in[11];
  const float* W3 = (const float*)d_in[12];
  const float* U3 = (const float*)d_in[13];
  const float* b3 = (const float*)d_in[14];
  const float* fcw = (const float*)d_in[15];
  const float* fcb = (const float*)d_in[16];

  float* out = (float*)d_out;                          // [16384][512]
  float* h_new = out + (size_t)B_ROWS * OUT_DIM;       // [16384][1024]
  float* c_new = h_new + (size_t)B_ROWS * HID_DIM;     // [16384][1024]

  unsigned short* wsA = (unsigned short*)d_ws;                 // 16384*1536
  unsigned short* wsWt = wsA + (size_t)B_ROWS * K_CAT;         // 4*1024*1536
  unsigned short* wsFc = wsWt + (size_t)4 * HID_DIM * K_CAT;   // 512*1024
  unsigned short* wsH = wsFc + (size_t)OUT_DIM * HID_DIM;      // 16384*1024
  // total ws: ~93 MB

  prep_cast_kernel<<<dim3(12544), dim3(256), 0, stream>>>(x, h, fcw, wsA, wsFc);
  pack_w_kernel<<<dim3(32, 48, 4), dim3(256), 0, stream>>>(W0, W1, W2, W3, U0, U1,
                                                           U2, U3, wsWt);
  lstm_gates_kernel<<<dim3(64, 16), dim3(512), 0, stream>>>(
      wsA, wsWt, c, b0, b1, b2, b3, h_new, c_new, wsH);
  fc_kernel<<<dim3(128, 4), dim3(256), 0, stream>>>(wsH, wsFc, fcb, out);
}

// Round 5
// 579.661 us; speedup vs baseline: 1.2603x; 1.2603x over previous
//
#include <hip/hip_runtime.h>
#include <stdint.h>

typedef float f32x4 __attribute__((ext_vector_type(4)));
typedef __bf16 bf16x8 __attribute__((ext_vector_type(8)));
typedef unsigned short u16x4 __attribute__((ext_vector_type(4)));
typedef unsigned short u16x8 __attribute__((ext_vector_type(8)));

#define B_ROWS 16384
#define IN_DIM 512
#define HID_DIM 1024
#define OUT_DIM 512
#define K_CAT 1536   // IN + HID
#define NT (K_CAT / 64)  // 24 K-tiles of 64

// ---------- helpers ----------

__device__ __forceinline__ unsigned short f2bf(float f) {
  unsigned u = __builtin_bit_cast(unsigned, f);
  unsigned r = u + 0x7fffu + ((u >> 16) & 1u);  // RNE
  return (unsigned short)(r >> 16);
}

__device__ __forceinline__ float sigmoidf_(float x) {
  return 1.f / (1.f + __expf(-x));
}
__device__ __forceinline__ float tanhf_(float x) {
  return 2.f / (1.f + __expf(-2.f * x)) - 1.f;
}

// async global->LDS, 16B per lane; LDS dest = wave-uniform base + lane*16
__device__ __forceinline__ void async16(const void* g, void* l) {
  const __attribute__((address_space(1))) unsigned int* gp =
      reinterpret_cast<const __attribute__((address_space(1))) unsigned int*>(
          reinterpret_cast<uintptr_t>(g));
  __attribute__((address_space(3))) unsigned int* lp =
      reinterpret_cast<__attribute__((address_space(3))) unsigned int*>(
          reinterpret_cast<uintptr_t>(l));
  __builtin_amdgcn_global_load_lds(gp, lp, 16, 0, 0);
}

// raw, undecorated barrier: the compiler decorates __builtin_amdgcn_s_barrier
// with s_waitcnt vmcnt(0), which kills the counted-vmcnt pipeline (R4 post-
// mortem: R2 landed exactly at the drain-class 750 TF; R4's 8 barriers/tile
// scaled the damage 1.75x). Opaque asm cannot be decorated; correctness is
// carried by the explicit counted vmcnt waits (see FIFO audit in comments).
__device__ __forceinline__ void raw_barrier() {
  asm volatile("s_barrier" ::: "memory");
}

// swizzled LDS fragment read: tile rows are 64 bf16 (128B = 8 x 16B slots),
// storage slot = logical kslot ^ (row & 7). Source side applies the same
// involution (pre-swizzled global address), LDS stays linear for
// global_load_lds (rule: both-sides-or-neither).
__device__ __forceinline__ bf16x8 frag_ld(const unsigned short* base, int row,
                                          int kslot) {
  return *(const bf16x8*)(base + row * 64 + (((kslot) ^ (row & 7)) << 3));
}

// ---------- P1: cast x||h -> bf16 A[16384][1536], fc_w -> bf16 ----------
// grid: 12544 * 256 threads == 3,145,728 (A/8) + 65,536 (fcw/8) exactly.

__global__ void prep_cast_kernel(const float* __restrict__ x,
                                 const float* __restrict__ h,
                                 const float* __restrict__ fcw,
                                 unsigned short* __restrict__ A,
                                 unsigned short* __restrict__ fcw16) {
  int gid = blockIdx.x * 256 + threadIdx.x;
  const int NA = B_ROWS * K_CAT / 8;
  const float* src;
  unsigned short* dst;
  if (gid < NA) {
    int flat = gid * 8;
    int row = flat / K_CAT;
    int col = flat - row * K_CAT;
    src = (col < IN_DIM) ? (x + (size_t)row * IN_DIM + col)
                         : (h + (size_t)row * HID_DIM + (col - IN_DIM));
    dst = A + flat;
  } else {
    int j = (gid - NA) * 8;
    src = fcw + j;
    dst = fcw16 + j;
  }
  f32x4 v0 = *(const f32x4*)src;
  f32x4 v1 = *(const f32x4*)(src + 4);
  u16x8 o;
  o[0] = f2bf(v0[0]); o[1] = f2bf(v0[1]); o[2] = f2bf(v0[2]); o[3] = f2bf(v0[3]);
  o[4] = f2bf(v1[0]); o[5] = f2bf(v1[1]); o[6] = f2bf(v1[2]); o[7] = f2bf(v1[3]);
  *(u16x8*)dst = o;
}

// ---------- P2: pack Wt[nb][k] bf16, nb = (h>>6)*256 + gate*64 + (h&63) ----
// So a 256-wide N-tile of the gates GEMM = all 4 gates x 64 h-columns.
// k < 512 -> W_g[k][h], else U_g[k-512][h]. Tiled transpose, block 256.

__global__ void pack_w_kernel(const float* __restrict__ W0, const float* __restrict__ W1,
                              const float* __restrict__ W2, const float* __restrict__ W3,
                              const float* __restrict__ U0, const float* __restrict__ U1,
                              const float* __restrict__ U2, const float* __restrict__ U3,
                              unsigned short* __restrict__ Wt) {
  __shared__ float tile[32][33];
  int g = blockIdx.z;
  int n0 = blockIdx.x * 32;
  int k0 = blockIdx.y * 32;
  const float* Wg = g == 0 ? W0 : g == 1 ? W1 : g == 2 ? W2 : W3;
  const float* Ug = g == 0 ? U0 : g == 1 ? U1 : g == 2 ? U2 : U3;
  int tx = threadIdx.x & 31, ty = threadIdx.x >> 5;
#pragma unroll
  for (int i = 0; i < 4; ++i) {
    int ky = ty + i * 8;
    int k = k0 + ky;
    float v = (k < IN_DIM) ? Wg[(size_t)k * HID_DIM + n0 + tx]
                           : Ug[(size_t)(k - IN_DIM) * HID_DIM + n0 + tx];
    tile[ky][tx] = v;
  }
  __syncthreads();
#pragma unroll
  for (int i = 0; i < 4; ++i) {
    int n = n0 + ty + i * 8;
    int nb = ((n >> 6) << 8) + (g << 6) + (n & 63);
    Wt[(size_t)nb * K_CAT + k0 + tx] = f2bf(tile[tx][ty + i * 8]);
  }
}

// ---------- G1: fused gates GEMM + LSTM cell ----------
// Block = 512 threads (8 waves, 2M x 4N). Tile 256 rows x 256 packed cols
// (= 64 h-cols x 4 gates) over K=1536, BK=64, double-buffered 128KB LDS.
// Staging: 8 rounds/tile (1 global_load_lds x 16B per thread per round):
// rounds 0-3 = B rows [64r,64r+64), rounds 4-7 = A row-groups {0,2,1,3}.
// Sync skeleton (R2, 274.5us) with RAW barriers so counted vmcnt survives:
//   q0 entry: vmcnt(2)+raw_barrier -> rounds 0-5 of this tile landed
//             (covers all q0/q1 ds_reads: B rows + A-groups 0,2)
//   q2 entry: vmcnt(4)+raw_barrier -> rounds 6,7 landed (A-groups 1,3,
//             read only in q2/q3); 4 of next tile's issues stay in flight
// WAR: ISSUE_ after the entry barrier targets the buffer whose last reads
// completed before every wave's prior-tile q3 MFMAs (compiler lgkm), hence
// before the barrier. ds_read->MFMA deps are compiler-managed (C++ loads).

template <int TAIL>
__device__ __forceinline__ void ktile(unsigned short* stage, int cur,
                                      const unsigned short* (&gp)[8],
                                      const int (&ldsoff)[8], int wm, int wn,
                                      int lane16, int quad, f32x4 (&acc)[8][4]) {
  const unsigned short* sB = stage + cur * 32768;
  const unsigned short* sA = sB + 16384;
  const int nxt = (cur ^ 1) * 65536;  // bytes
  bf16x8 bfr[4][2], af[2][2];

#define ISSUE_(r)                                     \
  if (!TAIL) {                                        \
    async16(gp[r], (char*)stage + nxt + ldsoff[r]);   \
    gp[r] += 64;                                      \
  }

#define READ_A_(q)                                    \
  {                                                   \
    const int r0 = wm * 128 + (q) * 32 + lane16;      \
    af[0][0] = frag_ld(sA, r0, quad);                 \
    af[0][1] = frag_ld(sA, r0, 4 + quad);             \
    af[1][0] = frag_ld(sA, r0 + 16, quad);            \
    af[1][1] = frag_ld(sA, r0 + 16, 4 + quad);        \
  }

#define MFMA_Q_(q)                                                        \
  __builtin_amdgcn_s_setprio(1);                                          \
  _Pragma("unroll") for (int nt = 0; nt < 4; ++nt) {                      \
    acc[2 * (q)][nt] = __builtin_amdgcn_mfma_f32_16x16x32_bf16(           \
        af[0][0], bfr[nt][0], acc[2 * (q)][nt], 0, 0, 0);                 \
    acc[2 * (q)][nt] = __builtin_amdgcn_mfma_f32_16x16x32_bf16(           \
        af[0][1], bfr[nt][1], acc[2 * (q)][nt], 0, 0, 0);                 \
    acc[2 * (q) + 1][nt] = __builtin_amdgcn_mfma_f32_16x16x32_bf16(       \
        af[1][0], bfr[nt][0], acc[2 * (q) + 1][nt], 0, 0, 0);             \
    acc[2 * (q) + 1][nt] = __builtin_amdgcn_mfma_f32_16x16x32_bf16(       \
        af[1][1], bfr[nt][1], acc[2 * (q) + 1][nt], 0, 0, 0);             \
  }                                                                       \
  __builtin_amdgcn_s_setprio(0);

  // ---- q0 ----
  asm volatile("s_waitcnt vmcnt(2)" ::: "memory");
  raw_barrier();
#pragma unroll
  for (int nt = 0; nt < 4; ++nt) {
    const int rb = wn * 64 + nt * 16 + lane16;
    bfr[nt][0] = frag_ld(sB, rb, quad);
    bfr[nt][1] = frag_ld(sB, rb, 4 + quad);
  }
  READ_A_(0);
  ISSUE_(0); ISSUE_(1);
  MFMA_Q_(0);
  // ---- q1 ----
  READ_A_(1);
  ISSUE_(2); ISSUE_(3);
  MFMA_Q_(1);
  // ---- q2 ----
  if (TAIL) {
    asm volatile("s_waitcnt vmcnt(0)" ::: "memory");
  } else {
    asm volatile("s_waitcnt vmcnt(4)" ::: "memory");
  }
  raw_barrier();
  READ_A_(2);
  ISSUE_(4); ISSUE_(5);
  MFMA_Q_(2);
  // ---- q3 ----
  READ_A_(3);
  ISSUE_(6); ISSUE_(7);
  MFMA_Q_(3);

#undef ISSUE_
#undef READ_A_
#undef MFMA_Q_
}

__global__ __launch_bounds__(512, 2) void lstm_gates_kernel(
    const unsigned short* __restrict__ A,   // [16384][1536] bf16
    const unsigned short* __restrict__ Wt,  // [4096][1536] bf16, packed rows
    const float* __restrict__ c_t,
    const float* __restrict__ b_i, const float* __restrict__ b_f,
    const float* __restrict__ b_o, const float* __restrict__ b_c,
    float* __restrict__ h_new, float* __restrict__ c_new,
    unsigned short* __restrict__ h_bf) {
  const int tid = threadIdx.x;
  const int wave = tid >> 6, lane = tid & 63;
  const int lane16 = lane & 15, quad = lane >> 4;
  const int wm = wave >> 2, wn = wave & 3;  // wave = wm*4 + wn
  const int m0 = blockIdx.x * 256;
  const int hb = blockIdx.y;  // 64 h-cols per tile

  __shared__ __align__(16) union {
    unsigned short stage[2][32768];  // per buf: B tile [256][64] | A tile [256][64]
    float act[4 * 64 * 68];          // epilogue: 4 gates x 64 rows x (64, stride 68)
  } U;

  // ---- staging setup: thread covers LDS bytes region + tid*16 ----
  const int srow = tid >> 3;   // row within a 64-row group
  const int sslot = tid & 7;   // 16B slot within a 128B row
  const int swz = (sslot ^ (srow & 7)) << 3;  // pre-swizzled source elem offset
  const unsigned short* gp[8];
  int ldsoff[8];
#pragma unroll
  for (int r = 0; r < 4; ++r) {  // B rounds
    gp[r] = Wt + (size_t)(hb * 256 + r * 64 + srow) * K_CAT + swz;
    ldsoff[r] = r * 8192 + wave * 1024;
  }
  {
    const int grp[4] = {0, 2, 1, 3};  // A row-group issue order (q0/q1 first)
#pragma unroll
    for (int i = 0; i < 4; ++i) {
      gp[4 + i] = A + (size_t)(m0 + grp[i] * 64 + srow) * K_CAT + swz;
      ldsoff[4 + i] = 32768 + grp[i] * 8192 + wave * 1024;
    }
  }

  f32x4 acc[8][4];
#pragma unroll
  for (int i = 0; i < 8; ++i)
#pragma unroll
    for (int j = 0; j < 4; ++j) {
      acc[i][j][0] = 0.f; acc[i][j][1] = 0.f; acc[i][j][2] = 0.f; acc[i][j][3] = 0.f;
    }

  unsigned short* stage = &U.stage[0][0];
  // prologue: tile 0 into buf 0 (8 rounds in flight)
#pragma unroll
  for (int r = 0; r < 8; ++r) {
    async16(gp[r], (char*)stage + ldsoff[r]);
    gp[r] += 64;
  }

  int cur = 0;
  for (int t = 0; t < NT - 1; ++t) {
    ktile<0>(stage, cur, gp, ldsoff, wm, wn, lane16, quad, acc);
    cur ^= 1;
  }
  ktile<1>(stage, cur, gp, ldsoff, wm, wn, lane16, quad, acc);

  __syncthreads();

  // ---- epilogue: activations + cell update, 4 passes of 64 rows ----
  float bv[4];
  const float* bgp = (wn == 0) ? b_i : (wn == 1) ? b_f : (wn == 2) ? b_o : b_c;
#pragma unroll
  for (int nt = 0; nt < 4; ++nt) bv[nt] = bgp[hb * 64 + nt * 16 + lane16];

#pragma unroll
  for (int c = 0; c < 4; ++c) {
    if (wm == (c >> 1)) {  // waves owning this 64-row band write their gate
#pragma unroll
      for (int mtl = 0; mtl < 4; ++mtl) {
#pragma unroll
        for (int nt = 0; nt < 4; ++nt)
#pragma unroll
          for (int r = 0; r < 4; ++r) {
            const int row = mtl * 16 + quad * 4 + r;  // 0..63 in pass
            const int col = nt * 16 + lane16;         // 0..63 h-col
            float v = acc[(c & 1) * 4 + mtl][nt][r] + bv[nt];
            float a = (wn < 3) ? sigmoidf_(v) : tanhf_(v);
            U.act[(wn * 64 + row) * 68 + col] = a;
          }
      }
    }
    __syncthreads();
    {
      const int row_l = tid >> 3;        // 0..63
      const int col0 = (tid & 7) * 8;    // 0..56
      const int grow = m0 + c * 64 + row_l;
      const size_t off = (size_t)grow * HID_DIM + hb * 64 + col0;
      u16x8 hbv;
#pragma unroll
      for (int half = 0; half < 2; ++half) {
        const int c4 = col0 + half * 4;
        f32x4 iv = *(const f32x4*)&U.act[(0 * 64 + row_l) * 68 + c4];
        f32x4 fv = *(const f32x4*)&U.act[(1 * 64 + row_l) * 68 + c4];
        f32x4 ov = *(const f32x4*)&U.act[(2 * 64 + row_l) * 68 + c4];
        f32x4 gv = *(const f32x4*)&U.act[(3 * 64 + row_l) * 68 + c4];
        f32x4 cold = *(const f32x4*)(c_t + off + half * 4);
        f32x4 cn, hn;
#pragma unroll
        for (int j = 0; j < 4; ++j) {
          float c2 = fv[j] * cold[j] + iv[j] * gv[j];
          float h2 = ov[j] * tanhf_(c2);
          cn[j] = c2;
          hn[j] = h2;
          hbv[half * 4 + j] = f2bf(h2);
        }
        *(f32x4*)(c_new + off + half * 4) = cn;
        *(f32x4*)(h_new + off + half * 4) = hn;
      }
      *(u16x8*)(h_bf + off) = hbv;
    }
    __syncthreads();
  }
}

// ---------- G2: out = h_new_bf16 @ fc_w^T + fc_b ----------
// m97-style 128x128 bt-GEMM; fc_w [512][1024] is already B^T layout.

__global__ __launch_bounds__(256, 2) void fc_kernel(
    const unsigned short* __restrict__ A,   // [16384][1024] bf16
    const unsigned short* __restrict__ Bt,  // [512][1024] bf16
    const float* __restrict__ bias, float* __restrict__ out) {
  const int m0 = blockIdx.x * 128;  // x = m: consecutive blocks share Bt slice
  const int n0 = blockIdx.y * 128;
  const int tid = threadIdx.x;
  const int wave = tid >> 6, lane = tid & 63;
  const int lane16 = lane & 15, quad = lane >> 4;
  const int wm = wave & 1, wn = wave >> 1;

  __shared__ __align__(16) unsigned short stage[8192];  // sA 128x32 | sB 128x32

  const unsigned short* gp[4];
  int ldsoff[4];
#pragma unroll
  for (int cc = 0; cc < 4; ++cc) {
    int chunk = wave * 4 + cc;
    ldsoff[cc] = chunk * 1024;
    int rr = lane >> 2;
    int col = (lane & 3) * 8;
    if (chunk < 8) {
      gp[cc] = A + (size_t)(m0 + chunk * 16 + rr) * HID_DIM + col;
    } else {
      gp[cc] = Bt + (size_t)(n0 + (chunk - 8) * 16 + rr) * HID_DIM + col;
    }
  }

  f32x4 acc[4][4];
#pragma unroll
  for (int i = 0; i < 4; ++i)
#pragma unroll
    for (int j = 0; j < 4; ++j) {
      acc[i][j][0] = 0.f; acc[i][j][1] = 0.f; acc[i][j][2] = 0.f; acc[i][j][3] = 0.f;
    }

  const unsigned short* sA = stage;
  const unsigned short* sB = stage + 4096;

  for (int kt = 0; kt < HID_DIM; kt += 32) {
#pragma unroll
    for (int cc = 0; cc < 4; ++cc) {
      async16(gp[cc], (char*)stage + ldsoff[cc]);
      gp[cc] += 32;
    }
    __syncthreads();
    bf16x8 a[4], b[4];
#pragma unroll
    for (int mt = 0; mt < 4; ++mt)
      a[mt] = *(const bf16x8*)(sA + (wm * 64 + mt * 16 + lane16) * 32 + quad * 8);
#pragma unroll
    for (int nt = 0; nt < 4; ++nt)
      b[nt] = *(const bf16x8*)(sB + (wn * 64 + nt * 16 + lane16) * 32 + quad * 8);
#pragma unroll
    for (int mt = 0; mt < 4; ++mt)
#pragma unroll
      for (int nt = 0; nt < 4; ++nt)
        acc[mt][nt] =
            __builtin_amdgcn_mfma_f32_16x16x32_bf16(a[mt], b[nt], acc[mt][nt], 0, 0, 0);
    __syncthreads();
  }

#pragma unroll
  for (int nt = 0; nt < 4; ++nt) {
    int gcol = n0 + wn * 64 + nt * 16 + lane16;
    float bb = bias[gcol];
#pragma unroll
    for (int mt = 0; mt < 4; ++mt) {
#pragma unroll
      for (int r = 0; r < 4; ++r) {
        int grow = m0 + wm * 64 + mt * 16 + quad * 4 + r;
        out[(size_t)grow * OUT_DIM + gcol] = acc[mt][nt][r] + bb;
      }
    }
  }
}

// ---------- launch ----------

extern "C" void kernel_launch(void* const* d_in, const int* in_sizes, int n_in,
                              void* d_out, int out_size, void* d_ws, size_t ws_size,
                              hipStream_t stream) {
  const float* x = (const float*)d_in[0];
  const float* h = (const float*)d_in[1];
  const float* c = (const float*)d_in[2];
  const float* W0 = (const float*)d_in[3];
  const float* U0 = (const float*)d_in[4];
  const float* b0 = (const float*)d_in[5];
  const float* W1 = (const float*)d_in[6];
  const float* U1 = (const float*)d_in[7];
  const float* b1 = (const float*)d_in[8];
  const float* W2 = (const float*)d_in[9];
  const float* U2 = (const float*)d_in[10];
  const float* b2 = (const float*)d_in[11];
  const float* W3 = (const float*)d_in[12];
  const float* U3 = (const float*)d_in[13];
  const float* b3 = (const float*)d_in[14];
  const float* fcw = (const float*)d_in[15];
  const float* fcb = (const float*)d_in[16];

  float* out = (float*)d_out;                          // [16384][512]
  float* h_new = out + (size_t)B_ROWS * OUT_DIM;       // [16384][1024]
  float* c_new = h_new + (size_t)B_ROWS * HID_DIM;     // [16384][1024]

  unsigned short* wsA = (unsigned short*)d_ws;                 // 16384*1536
  unsigned short* wsWt = wsA + (size_t)B_ROWS * K_CAT;         // 4*1024*1536
  unsigned short* wsFc = wsWt + (size_t)4 * HID_DIM * K_CAT;   // 512*1024
  unsigned short* wsH = wsFc + (size_t)OUT_DIM * HID_DIM;      // 16384*1024
  // total ws: ~93 MB

  prep_cast_kernel<<<dim3(12544), dim3(256), 0, stream>>>(x, h, fcw, wsA, wsFc);
  pack_w_kernel<<<dim3(32, 48, 4), dim3(256), 0, stream>>>(W0, W1, W2, W3, U0, U1,
                                                           U2, U3, wsWt);
  lstm_gates_kernel<<<dim3(64, 16), dim3(512), 0, stream>>>(
      wsA, wsWt, c, b0, b1, b2, b3, h_new, c_new, wsH);
  fc_kernel<<<dim3(128, 4), dim3(256), 0, stream>>>(wsH, wsFc, fcb, out);
}